// Round 1
// baseline (88.767 us; speedup 1.0000x reference)
//
#include <hip/hip_runtime.h>

// 4-qubit, 2-layer QML circuit, B=1M samples, one thread/sample.
// Single fused kernel: weight-only trig is recomputed per thread in
// registers (wave-uniform, ~16 transcendentals) instead of a separate
// 1-block precompute kernel + 64 per-thread table loads. This removes a
// serialized graph node and all global traffic except x (16 MB) and
// out (16 MB).
//
// Flat amp index n = q0*8 + q1*4 + q2*2 + q3 (qubit 0 = bit 3).
// Per layer: RX(x_q) per-sample, RY(w0) RZ(w1) weight-only, CNOT chain.
//
// Layer 1 on |0000>: product state; per qubit
//   v = RZ*RY*RX|0> with only 4 distinct weight products
//   p1=cz*cy p2=sz*cy p3=cz*sy p4=sz*sy:
//   v0 = ( p1*c + p4*s, -p2*c + p3*s)
//   v1 = ( p3*c + p2*s,  p4*c - p1*s)
// Layer 2: U = (RZ*RY)*RX is SU(2): U = [[al, be],[-conj(be), conj(al)]]
//   al = ( c*p1 + s*p4, -c*p2 + s*p3)
//   be = (-c*p3 - s*p2,  c*p4 - s*p1)

struct C2 { float r, i; };

__device__ __forceinline__ C2 cmul(C2 a, C2 b) {
    C2 o;
    o.r = a.r * b.r - a.i * b.i;
    o.i = a.r * b.i + a.i * b.r;
    return o;
}

__device__ __forceinline__ void cnot_chain(C2 st[16]) {
    // CNOT(0,1): q0=1 -> flip q1: swap n=8..11 <-> 12..15
    #pragma unroll
    for (int j = 0; j < 4; j++) { C2 t = st[8 + j]; st[8 + j] = st[12 + j]; st[12 + j] = t; }
    // CNOT(1,2): q1=1 -> flip q2: swap (4,6),(5,7),(12,14),(13,15)
    {
        C2 t;
        t = st[4];  st[4]  = st[6];  st[6]  = t;
        t = st[5];  st[5]  = st[7];  st[7]  = t;
        t = st[12]; st[12] = st[14]; st[14] = t;
        t = st[13]; st[13] = st[15]; st[15] = t;
    }
    // CNOT(2,3): q2=1 -> flip q3: swap (2,3),(6,7),(10,11),(14,15)
    {
        C2 t;
        t = st[2];  st[2]  = st[3];  st[3]  = t;
        t = st[6];  st[6]  = st[7];  st[7]  = t;
        t = st[10]; st[10] = st[11]; st[11] = t;
        t = st[14]; st[14] = st[15]; st[15] = t;
    }
}

__global__ void __launch_bounds__(256) qml_kernel(
        const float* __restrict__ x, const float* __restrict__ w,
        float* __restrict__ out, int batch) {
    int tid = blockIdx.x * blockDim.x + threadIdx.x;
    if (tid >= batch) return;

    float4 xv = reinterpret_cast<const float4*>(x)[tid];
    float c[4], s[4];
    __sincosf(0.5f * xv.x, &s[0], &c[0]);
    __sincosf(0.5f * xv.y, &s[1], &c[1]);
    __sincosf(0.5f * xv.z, &s[2], &c[2]);
    __sincosf(0.5f * xv.w, &s[3], &c[3]);

    // ---- layer 1: product state, per-qubit 2-vectors ----
    // w layout: w[l*8 + q*2 + {ry,rz}]
    C2 v[4][2];
    #pragma unroll
    for (int q = 0; q < 4; q++) {
        float sy, cy, sz, cz;
        __sincosf(0.5f * w[q * 2 + 0], &sy, &cy);
        __sincosf(0.5f * w[q * 2 + 1], &sz, &cz);
        float p1 = cz * cy, p2 = sz * cy, p3 = cz * sy, p4 = sz * sy;
        v[q][0].r =  p1 * c[q] + p4 * s[q];
        v[q][0].i = -p2 * c[q] + p3 * s[q];
        v[q][1].r =  p3 * c[q] + p2 * s[q];
        v[q][1].i =  p4 * c[q] - p1 * s[q];
    }

    // ---- tensor expansion to 16 amps ----
    C2 t01[4], t23[4], st[16];
    #pragma unroll
    for (int a = 0; a < 2; a++)
        #pragma unroll
        for (int b = 0; b < 2; b++) {
            t01[a * 2 + b] = cmul(v[0][a], v[1][b]);
            t23[a * 2 + b] = cmul(v[2][a], v[3][b]);
        }
    #pragma unroll
    for (int a = 0; a < 4; a++)
        #pragma unroll
        for (int b = 0; b < 4; b++)
            st[a * 4 + b] = cmul(t01[a], t23[b]);

    cnot_chain(st);

    // ---- layer 2: fused SU(2) gate per qubit ----
    #pragma unroll
    for (int q = 0; q < 4; q++) {
        float sy, cy, sz, cz;
        __sincosf(0.5f * w[8 + q * 2 + 0], &sy, &cy);
        __sincosf(0.5f * w[8 + q * 2 + 1], &sz, &cz);
        float p1 = cz * cy, p2 = sz * cy, p3 = cz * sy, p4 = sz * sy;
        float ar =  c[q] * p1 + s[q] * p4;
        float ai = -c[q] * p2 + s[q] * p3;
        float br = -c[q] * p3 - s[q] * p2;
        float bi =  c[q] * p4 - s[q] * p1;
        int bit = 8 >> q;
        #pragma unroll
        for (int n0 = 0; n0 < 16; n0++) {
            if (n0 & bit) continue;
            int n1 = n0 | bit;
            C2 a0 = st[n0], a1 = st[n1];
            // n0' = al*a0 + be*a1 ; n1' = -conj(be)*a0 + conj(al)*a1
            st[n0].r =  ar * a0.r - ai * a0.i + br * a1.r - bi * a1.i;
            st[n0].i =  ar * a0.i + ai * a0.r + br * a1.i + bi * a1.r;
            st[n1].r = -br * a0.r - bi * a0.i + ar * a1.r + ai * a1.i;
            st[n1].i = -br * a0.i + bi * a0.r + ar * a1.i - ai * a1.r;
        }
    }

    cnot_chain(st);

    // ---- probabilities and <Z_i> ----
    float p[16];
    #pragma unroll
    for (int n = 0; n < 16; n++) p[n] = st[n].r * st[n].r + st[n].i * st[n].i;

    float a8[8], z3 = 0.f;
    #pragma unroll
    for (int m = 0; m < 8; m++) { a8[m] = p[2 * m] + p[2 * m + 1]; z3 += p[2 * m] - p[2 * m + 1]; }
    float b4[4], z2 = 0.f;
    #pragma unroll
    for (int k = 0; k < 4; k++) { b4[k] = a8[2 * k] + a8[2 * k + 1]; z2 += a8[2 * k] - a8[2 * k + 1]; }
    float z1 = (b4[0] - b4[1]) + (b4[2] - b4[3]);
    float z0 = (b4[0] + b4[1]) - (b4[2] + b4[3]);

    reinterpret_cast<float4*>(out)[tid] = make_float4(z0, z1, z2, z3);
}

extern "C" void kernel_launch(void* const* d_in, const int* in_sizes, int n_in,
                              void* d_out, int out_size, void* d_ws, size_t ws_size,
                              hipStream_t stream) {
    const float* x = (const float*)d_in[0];      // [B,4]
    const float* w = (const float*)d_in[1];      // [2,4,2]
    float* out = (float*)d_out;                  // [B,4]
    int batch = in_sizes[0] / 4;

    int block = 256;
    int grid = (batch + block - 1) / block;
    qml_kernel<<<grid, block, 0, stream>>>(x, w, out, batch);
}